// Round 9
// baseline (1356.242 us; speedup 1.0000x reference)
//
#include <hip/hip_runtime.h>
#include <stdint.h>

// ---------------------------------------------------------------------------
// MultiHeadAdaptiveChebyshevLayer, round 11: persistent 4-row blocks with
// register-resident x/scale (no xs LDS tile, no staging barrier).
//
// Model (R0..R8 counters): fixed harness tax ~214 us; R0-main ~105 us =
// 4 rows x (compute ~13 || store ~10) fully SERIALIZED because the two
// resident blocks are phase-locked and each block's store burst follows its
// reduction barrier.  R8 (regular vs NT stores) was neutral -> not a store-
// semantics problem; it's phase structure.  R6's persistent attempt failed
// on (a) spill at the (1024,4)->64-reg target and (b) an end-of-loop
// __syncthreads that drained vmcnt (stores) every row.
//
// This version: thread t needs only x[(c&1)*512 + (t>>1)] (2 values/row)
// and scale[(c>>1)*1024 + (c&1)*512 + (t>>1)] (16 values, row-invariant ->
// preloaded ONCE into registers for all 4 rows).  So: no LDS tile, no
// staging, one barrier per row (reduction, double-buffered red[]).  At that
// barrier the only outstanding vmem is the previous row's stores (~9 us
// old = drained) -> the compiler's vmcnt(0)-before-barrier is free.  NT
// stores (bypass L2) keep the 1 MiB W3 table L2-resident for re-reads.
// (1024,1): R3-proven no-spill regime; live ~88 regs; LDS=256B; 1 blk/CU.
//
// Ownership per row: thread t owns f = c*4096 + t*4 + {0..3}, c=0..15;
// W3[(c*4+d)*1024+t] = folded bf16x8 coeffs, GB3[c*1024+t] = packed g/b.
// ---------------------------------------------------------------------------

#define LN_EPS 1e-5f

typedef float vfloat4 __attribute__((ext_vector_type(4)));

__device__ __forceinline__ unsigned bf16_rne(float f) {
    unsigned u = __float_as_uint(f);
    unsigned r = u + 0x7fffu + ((u >> 16) & 1u);
    return r >> 16;
}
__device__ __forceinline__ float bf_lo(unsigned u) { return __uint_as_float(u << 16); }
__device__ __forceinline__ float bf_hi(unsigned u) { return __uint_as_float(u & 0xffff0000u); }

// Prologue 1: fold poly into kernel, bf16-pack over m, permute so that the
// main kernel's load for (c,d) at lane t is W3[(c*4+d)*1024 + t].
__global__ void fold_weights_kernel(const float* __restrict__ K,
                                    const float* __restrict__ poly,
                                    uint4* __restrict__ W3) {
    int tid = blockIdx.x * blockDim.x + threadIdx.x;   // [0, 65536)
    int p = tid >> 3, k = tid & 7;
    const float* kp = K + (size_t)p * 64 + k;          // stride 8 over m
    float pw = poly[p * 8 + k];
    float v[8];
#pragma unroll
    for (int m = 0; m < 8; ++m) v[m] = kp[m * 8] * pw;
    uint4 q;
    q.x = bf16_rne(v[0]) | (bf16_rne(v[1]) << 16);
    q.y = bf16_rne(v[2]) | (bf16_rne(v[3]) << 16);
    q.z = bf16_rne(v[4]) | (bf16_rne(v[5]) << 16);
    q.w = bf16_rne(v[6]) | (bf16_rne(v[7]) << 16);
    int c = p >> 9;
    int t = ((p & 511) << 1) | (k >> 2);
    int d = k & 3;
    W3[(c * 4 + d) * 1024 + t] = q;
}

// Prologue 2: GB3[tid] covers features f = tid*4 .. +3, each word packs
// (bf16(gamma) | bf16(beta)<<16).  Main kernel reads GB3[c*1024 + t].
__global__ void pack_gb_kernel(const float* __restrict__ gamma,
                               const float* __restrict__ beta,
                               uint4* __restrict__ GB3) {
    int tid = blockIdx.x * blockDim.x + threadIdx.x;   // [0, 16384)
    float4 g = ((const float4*)gamma)[tid];
    float4 b = ((const float4*)beta)[tid];
    uint4 q;
    q.x = bf16_rne(g.x) | (bf16_rne(b.x) << 16);
    q.y = bf16_rne(g.y) | (bf16_rne(b.y) << 16);
    q.z = bf16_rne(g.z) | (bf16_rne(b.z) << 16);
    q.w = bf16_rne(g.w) | (bf16_rne(b.w) << 16);
    GB3[tid] = q;
}

// 8-term Chebyshev dot against one packed-bf16 quad (T1..T7 in scope).
#define CHEB_DOT(q, acc)                                                      \
    {                                                                         \
        float c0 = bf_lo(q.x), c1 = bf_hi(q.x);                               \
        float c2 = bf_lo(q.y), c3 = bf_hi(q.y);                               \
        float c4 = bf_lo(q.z), c5 = bf_hi(q.z);                               \
        float c6 = bf_lo(q.w), c7 = bf_hi(q.w);                               \
        acc = fmaf(T1, c1, c0);                                               \
        acc = fmaf(T2, c2, acc);                                              \
        acc = fmaf(T3, c3, acc);                                              \
        acc = fmaf(T4, c4, acc);                                              \
        acc = fmaf(T5, c5, acc);                                              \
        acc = fmaf(T6, c6, acc);                                              \
        acc = fmaf(T7, c7, acc);                                              \
    }

// Main: persistent blocks — grid 256 (1/CU), each block does rows
// 4*b .. 4*b+3.  (1024,1): no-spill regime (R3 evidence); live ~88 regs.
__global__ __launch_bounds__(1024, 1) void cheb_ln_main(
    const float* __restrict__ x, const float* __restrict__ scale,
    const uint4* __restrict__ W3, const uint4* __restrict__ GB3,
    float* __restrict__ out) {
    __shared__ float red[64];        // double-buffered: 32 per row parity
    const int t = threadIdx.x;
    const int w = t >> 6, l = t & 63;
    const int phalf = t >> 1;

    // Row-invariant: 16 scale values for this thread, preloaded once.
    // v(c) = x[(c&1)*512 + phalf] * sc[c],  sc[c] = scale[(c>>1)*1024 +
    // (c&1)*512 + phalf].  (Equivalent to R0's xs[c*512+phalf].)
    float sc[16];
#pragma unroll
    for (int c = 0; c < 16; ++c)
        sc[c] = scale[(c >> 1) * 1024 + (c & 1) * 512 + phalf];

#pragma unroll 1
    for (int j = 0; j < 4; ++j) {
        const int r = (blockIdx.x << 2) + j;
        const float* xrow = x + (size_t)r * 1024;
        float xv0 = xrow[phalf];
        float xv1 = xrow[512 + phalf];

        unsigned y2[32];            // 64 y values as packed bf16 pairs
        float sum = 0.f, sq = 0.f;

#pragma unroll
        for (int c = 0; c < 16; ++c) {
            float v = ((c & 1) ? xv1 : xv0) * sc[c];
            float v2 = v + v;
            float T1 = v;
            float T2 = fmaf(v2, T1, -1.f);
            float T3 = fmaf(v2, T2, -T1);
            float T4 = fmaf(v2, T3, -T2);
            float T5 = fmaf(v2, T4, -T3);
            float T6 = fmaf(v2, T5, -T4);
            float T7 = fmaf(v2, T6, -T5);

            uint4 q0 = W3[(c * 4 + 0) * 1024 + t];
            uint4 q1 = W3[(c * 4 + 1) * 1024 + t];
            uint4 q2 = W3[(c * 4 + 2) * 1024 + t];
            uint4 q3 = W3[(c * 4 + 3) * 1024 + t];

            float a0, a1, a2, a3;
            CHEB_DOT(q0, a0);
            CHEB_DOT(q1, a1);
            CHEB_DOT(q2, a2);
            CHEB_DOT(q3, a3);

            sum += (a0 + a1) + (a2 + a3);
            sq = fmaf(a0, a0, sq); sq = fmaf(a1, a1, sq);
            sq = fmaf(a2, a2, sq); sq = fmaf(a3, a3, sq);
            y2[c * 2 + 0] = bf16_rne(a0) | (bf16_rne(a1) << 16);
            y2[c * 2 + 1] = bf16_rne(a2) | (bf16_rne(a3) << 16);
        }

        // Wave reduce, then cross-wave via double-buffered red[] — the only
        // barrier in the row.  Outstanding vmem here = previous row's NT
        // stores, issued a full compute-phase ago -> vmcnt(0) is free.
#pragma unroll
        for (int off = 32; off; off >>= 1) {
            sum += __shfl_down(sum, off, 64);
            sq  += __shfl_down(sq,  off, 64);
        }
        const int ro = (j & 1) << 5;
        if (l == 0) { red[ro + w] = sum; red[ro + 16 + w] = sq; }
        __syncthreads();
        float S = 0.f, SQ = 0.f;
#pragma unroll
        for (int q = 0; q < 16; ++q) { S += red[ro + q]; SQ += red[ro + 16 + q]; }
        const float inv = 1.f / 65536.f;
        float mu = S * inv;
        float var = fmaf(-mu, mu, SQ * inv);
        float rstd = rsqrtf(var + LN_EPS);

        // Epilogue: NT stores (bypass L2 -> W3 stays L2-resident).  Stores
        // drain in the background of the next row's compute.
        float* orow = out + (size_t)r * 65536;
#pragma unroll
        for (int c = 0; c < 16; ++c) {
            uint4 g = GB3[c * 1024 + t];
            unsigned u0 = y2[c * 2 + 0], u1 = y2[c * 2 + 1];
            vfloat4 o;
            o.x = fmaf((bf_lo(u0) - mu) * rstd, bf_lo(g.x), bf_hi(g.x));
            o.y = fmaf((bf_hi(u0) - mu) * rstd, bf_lo(g.y), bf_hi(g.y));
            o.z = fmaf((bf_lo(u1) - mu) * rstd, bf_lo(g.z), bf_hi(g.z));
            o.w = fmaf((bf_hi(u1) - mu) * rstd, bf_lo(g.w), bf_hi(g.w));
            __builtin_nontemporal_store(o, (vfloat4*)(orow + c * 4096 + t * 4));
        }
        // NO end-of-row barrier: next row's compute proceeds immediately;
        // red[] safety comes from the parity double-buffer.
    }
}

extern "C" void kernel_launch(void* const* d_in, const int* in_sizes, int n_in,
                              void* d_out, int out_size, void* d_ws, size_t ws_size,
                              hipStream_t stream) {
    const float* x     = (const float*)d_in[0];   // [1024,1024]
    const float* scale = (const float*)d_in[1];   // [8,1024]
    const float* poly  = (const float*)d_in[2];   // [8,1024,8]
    const float* kern  = (const float*)d_in[3];   // [8,1024,8,8]
    const float* gamma = (const float*)d_in[4];   // [65536]
    const float* beta  = (const float*)d_in[5];   // [65536]
    float* out = (float*)d_out;

    uint4* W3  = (uint4*)d_ws;                          // 1 MiB
    uint4* GB3 = (uint4*)((char*)d_ws + (1u << 20));    // 256 KiB

    fold_weights_kernel<<<256, 256, 0, stream>>>(kern, poly, W3);
    pack_gb_kernel<<<64, 256, 0, stream>>>(gamma, beta, GB3);
    cheb_ln_main<<<256, 1024, 0, stream>>>(x, scale, W3, GB3, out);
}